// Round 12
// baseline (202.187 us; speedup 1.0000x reference)
//
#include <hip/hip_runtime.h>
#include <hip/hip_bf16.h>
#include <math.h>

#define N_NODES 10000
#define CAP 192        // padded bucket capacity per node (max in-degree ~99 here)
#define CSTRIDE 16     // counter stride in ints: one counter per 64B cache line

typedef __attribute__((ext_vector_type(8))) short short8;
typedef __attribute__((ext_vector_type(8))) unsigned short ushort8;
typedef __attribute__((ext_vector_type(4))) unsigned short ushort4v;
typedef __attribute__((ext_vector_type(4))) float f32x4;

__device__ inline float b2f(unsigned short u) {
  union { unsigned int i; float f; } c;
  c.i = ((unsigned int)u) << 16;
  return c.f;
}
__device__ inline unsigned short f2bu(float v) {
  __hip_bfloat16 h = __float2bfloat16(v);
  return *(unsigned short*)&h;
}
__device__ inline float asf(unsigned int u) {
  union { unsigned int i; float f; } c;
  c.i = u;
  return c.f;
}

// ---- packed f32 (VOP3P, dual-pipe) ----
__device__ inline float2 pk_add(float2 a, float2 b) {
  float2 d;
  asm("v_pk_add_f32 %0, %1, %2" : "=v"(d) : "v"(a), "v"(b));
  return d;
}
__device__ inline float2 pk_mul(float2 a, float2 b) {
  float2 d;
  asm("v_pk_mul_f32 %0, %1, %2" : "=v"(d) : "v"(a), "v"(b));
  return d;
}
__device__ inline float2 pk_fma(float2 a, float2 b, float2 c) {
  float2 d;
  asm("v_pk_fma_f32 %0, %1, %2, %3" : "=v"(d) : "v"(a), "v"(b), "v"(c));
  return d;
}

// row_ror DPP add: x += rotate-within-row-of-16(x, CTRL). Pure VALU.
template <int CTRL>
__device__ inline float dpp_radd(float x) {
  union { float f; int i; } u, v;
  u.f = x;
  v.i = __builtin_amdgcn_update_dpp(0, u.i, CTRL, 0xf, 0xf, true);
  return x + v.f;
}

// ---------------- fused prep: bucket-fill + W transposes + x convert -------
struct PrepArgs {
  const int* src;
  const int* dst;
  int E;
  int FB, WT, XB;
  int* cnt;        // [N_NODES*CSTRIDE] zeroed; counter at node*CSTRIDE
  int* csr_pad;    // [N_NODES*CAP]
  const float* wsrc[6];
  unsigned short* wdst[6];
  int K[6], O[6], toff[6];
  const float* x;
  unsigned short* xb;
  int xn4;
};

__global__ void __launch_bounds__(256) prep_k(PrepArgs a) {
  const int bx = blockIdx.x;
  const int tid = threadIdx.x;
  if (bx < a.FB) {  // ---- bucket fill ----
    const int i = bx * 256 + tid;
    if (i < a.E) {
      const int d = a.dst[i];
      const int pos = atomicAdd(&a.cnt[d * CSTRIDE], 1);
      if (pos < CAP) a.csr_pad[d * CAP + pos] = a.src[i];
    }
  } else if (bx < a.FB + a.WT) {  // ---- W transpose, 32x32 tile ----
    const int t = bx - a.FB;
    int m = 0;
#pragma unroll
    for (int i = 1; i < 6; ++i) m += (t >= a.toff[i]);
    const int K = a.K[m], O = a.O[m];
    const int tl = t - a.toff[m];
    const int tilesO = O >> 5;
    const int k0 = (tl / tilesO) << 5;
    const int o0 = (tl - (tl / tilesO) * tilesO) << 5;
    __shared__ float lds[32][33];
    const float* s = a.wsrc[m];
    unsigned short* d = a.wdst[m];
    const int c = tid & 31, r8 = tid >> 5;
#pragma unroll
    for (int p = 0; p < 4; ++p) {
      const int r = p * 8 + r8;
      lds[r][c] = s[(size_t)(k0 + r) * O + o0 + c];  // coalesced f32 read
    }
    __syncthreads();
#pragma unroll
    for (int p = 0; p < 4; ++p) {
      const int rr = p * 8 + r8;
      d[(size_t)(o0 + rr) * K + k0 + c] = f2bu(lds[c][rr]);  // coalesced write
    }
  } else {  // ---- x convert ----
    const int i4 = (bx - a.FB - a.WT) * 256 + tid;
    if (i4 < a.xn4) {
      const float4 v = ((const float4*)a.x)[i4];
      ushort4v o;
      o.x = f2bu(v.x); o.y = f2bu(v.y); o.z = f2bu(v.z); o.w = f2bu(v.w);
      *(ushort4v*)&a.xb[(size_t)i4 * 4] = o;
    }
  }
}

// ---------------- bf16 MFMA GEMM with B-tile staged in LDS ----------------

template <int K, int O>
__global__ void __launch_bounds__(256) mfma_gemm_k(
    const unsigned short* __restrict__ Xb, const unsigned short* __restrict__ WtL,
    const unsigned short* __restrict__ WtR, unsigned short* __restrict__ xlb,
    unsigned short* __restrict__ xrb) {
  constexpr int BSTR = K + 8;  // LDS row stride (ushorts)
  __shared__ unsigned short Bs[64 * BSTR];
  const int tid = threadIdx.x;
  const int wv = tid >> 6, lane = tid & 63;
  const int rowBase = blockIdx.x * 64 + wv * 16;
  const int colBase = blockIdx.y * 64;
  const unsigned short* __restrict__ Wt = blockIdx.z ? WtR : WtL;
  unsigned short* __restrict__ Y = blockIdx.z ? xrb : xlb;
  const int lr = lane & 15, lh = lane >> 4;

  {
    const unsigned short* bsrc = Wt + (size_t)colBase * K;
    constexpr int CHUNKS = 64 * K / 8;
#pragma unroll
    for (int c8 = 0; c8 < CHUNKS / 256; ++c8) {
      const int chunk = c8 * 256 + tid;
      const int r = chunk / (K / 8);
      const int o = (chunk - r * (K / 8)) * 8;
      *(ushort8*)&Bs[r * BSTR + o] = *(const ushort8*)&bsrc[(size_t)r * K + o];
    }
  }
  __syncthreads();

  int arow = rowBase + lr;
  if (arow >= N_NODES) arow = 0;  // clamp (loads only; stores guarded)
  const unsigned short* __restrict__ aptr = Xb + (size_t)arow * K + lh * 8;

  f32x4 acc[4] = {f32x4{0,0,0,0}, f32x4{0,0,0,0}, f32x4{0,0,0,0}, f32x4{0,0,0,0}};
#pragma unroll
  for (int kt = 0; kt < K; kt += 32) {
    const short8 a = *(const short8*)(aptr + kt);
#pragma unroll
    for (int c = 0; c < 4; ++c) {
      const short8 b = *(const short8*)&Bs[(c * 16 + lr) * BSTR + kt + lh * 8];
      acc[c] = __builtin_amdgcn_mfma_f32_16x16x32_bf16(a, b, acc[c], 0, 0, 0);
    }
  }
#pragma unroll
  for (int c = 0; c < 4; ++c) {
#pragma unroll
    for (int q = 0; q < 4; ++q) {
      const int r = rowBase + lh * 4 + q;
      if (r < N_NODES) Y[(size_t)r * O + colBase + c * 16 + lr] = f2bu(acc[c][q]);
    }
  }
}

// ---------------- per-dst-node online-softmax aggregation v8 ----------------
// R7 structure + packed-f32 (VOP3P) channel math. Score uses exact
// leaky(t) = max(t, 0.2t):  p = sum a_k * max(t_k, 0.2 t_k).
// Channels processed as float2 pairs: pk_add / pk_mul / pk_fma.

template <int O, bool FINAL>
__global__ void __launch_bounds__(256, 4) agg8_k(
    const unsigned short* __restrict__ xlb, const unsigned short* __restrict__ xrb,
    const float* __restrict__ att, const float* __restrict__ bias,
    const int* __restrict__ cnt, const int* __restrict__ csr_pad,
    void* __restrict__ outp) {
  constexpr int NCH = O / 16;   // channels per lane (16 or 8)
  constexpr int NP = NCH / 2;   // float2 pairs per lane (8 or 4)
  __shared__ float sm[2], ss[2], sacc[2][O];
  const int tid = threadIdx.x;
  const int wv = tid >> 6;
  const int lane = tid & 63;
  const int nloc = wv >> 1;
  const int half = wv & 1;
  const int node = blockIdx.x * 2 + nloc;
  const int cl = lane & 15;   // channel group (low bits -> DPP row = edge)
  const int e_sub = lane >> 4;
  const int ch0 = cl * NCH;

  float2 av2[NP], xrv2[NP], acc2[NP];
#pragma unroll
  for (int j = 0; j < NP; ++j) {
    av2[j] = make_float2(att[ch0 + 2 * j], att[ch0 + 2 * j + 1]);
    xrv2[j] = make_float2(b2f(xrb[(size_t)node * O + ch0 + 2 * j]),
                          b2f(xrb[(size_t)node * O + ch0 + 2 * j + 1]));
    acc2[j] = make_float2(0.f, 0.f);
  }
  const float2 c02 = make_float2(0.2f, 0.2f);
  const int beg = node * CAP;
  const int deg = min(cnt[node * CSTRIDE], CAP);
  const int h0 = (deg + 1) >> 1;
  const int b = half ? beg + h0 : beg;
  const int e_end = half ? beg + deg : beg + h0;

  float m = -INFINITY, s = 0.f;
  if (b < e_end) {
    const int e_last = e_end - 1;
    const int G = (e_end - b + 3) >> 2;
    const int G3 = ((G + 2) / 3) * 3;
    auto idx_of = [&](int g) -> int {
      int ei = b + 4 * g + e_sub;
      return csr_pad[ei < e_last ? ei : e_last];
    };
    ushort8 lo0, hi0, lo1, hi1, lo2, hi2;
    {
      const int i0 = idx_of(0), i1 = idx_of(1), i2 = idx_of(2);
      const ushort8* r0 = (const ushort8*)(xlb + (size_t)i0 * O + ch0);
      const ushort8* r1 = (const ushort8*)(xlb + (size_t)i1 * O + ch0);
      const ushort8* r2 = (const ushort8*)(xlb + (size_t)i2 * O + ch0);
      lo0 = r0[0]; lo1 = r1[0]; lo2 = r2[0];
      if constexpr (NCH == 16) { hi0 = r0[1]; hi1 = r1[1]; hi2 = r2[1]; }
    }
    int jA = idx_of(3), jB = idx_of(4), jC = idx_of(5);

    auto step = [&](ushort8& lo, ushort8& hi, int& jref, int g, int gref) {
      // ---- extract bf16 pairs -> float2 (1 lshl + 1 and per pair) ----
      float2 xf2[NP];
      {
        const unsigned int* lw = (const unsigned int*)&lo;
#pragma unroll
        for (int j = 0; j < 4; ++j)
          xf2[j] = make_float2(asf(lw[j] << 16), asf(lw[j] & 0xffff0000u));
        if constexpr (NCH == 16) {
          const unsigned int* hw = (const unsigned int*)&hi;
#pragma unroll
          for (int j = 0; j < 4; ++j)
            xf2[4 + j] = make_float2(asf(hw[j] << 16), asf(hw[j] & 0xffff0000u));
        }
      }
      // ---- score: p = sum a * max(t, 0.2t), packed, 2 dep chains ----
      float2 pA = make_float2(0.f, 0.f), pB = make_float2(0.f, 0.f);
#pragma unroll
      for (int j = 0; j < NP; j += 2) {
        float2 t = pk_add(xf2[j], xrv2[j]);
        float2 u = pk_mul(t, c02);
        u.x = fmaxf(t.x, u.x);
        u.y = fmaxf(t.y, u.y);
        pA = pk_fma(av2[j], u, pA);
        float2 t2 = pk_add(xf2[j + 1], xrv2[j + 1]);
        float2 u2 = pk_mul(t2, c02);
        u2.x = fmaxf(t2.x, u2.x);
        u2.y = fmaxf(t2.y, u2.y);
        pB = pk_fma(av2[j + 1], u2, pB);
      }
      float p = (pA.x + pA.y) + (pB.x + pB.y);
      if (b + 4 * g + e_sub >= e_end) p = -INFINITY;
      // 16-lane row sum, pure VALU (DPP row_ror 1,2,4,8)
      p = dpp_radd<0x121>(p);
      p = dpp_radd<0x122>(p);
      p = dpp_radd<0x124>(p);
      p = dpp_radd<0x128>(p);
      // defer-max: rescale only when new max exceeds m+8
      if (!__all(p <= m + 8.f)) {
        float q = fmaxf(p, __shfl_xor(p, 16, 64));
        q = fmaxf(q, __shfl_xor(q, 32, 64));
        const float f = __expf(m - q);
        const float2 f2 = make_float2(f, f);
        s *= f;
#pragma unroll
        for (int j = 0; j < NP; ++j) acc2[j] = pk_mul(f2, acc2[j]);
        m = q;
      }
      const float w = __expf(p - m);
      s += w;
      const float2 w2 = make_float2(w, w);
#pragma unroll
      for (int j = 0; j < NP; ++j) acc2[j] = pk_fma(w2, xf2[j], acc2[j]);
      // reissue rows for g+3 into this slot, idx for g+6
      const ushort8* rp = (const ushort8*)(xlb + (size_t)jref * O + ch0);
      lo = rp[0];
      if constexpr (NCH == 16) hi = rp[1];
      jref = idx_of(gref);
    };

    for (int g = 0; g < G3; g += 3) {
      step(lo0, hi0, jA, g, g + 6);
      step(lo1, hi1, jB, g + 1, g + 7);
      step(lo2, hi2, jC, g + 2, g + 8);
    }
  }
  // cross-row collapse (once per wave)
  s += __shfl_xor(s, 16, 64);
  s += __shfl_xor(s, 32, 64);
#pragma unroll
  for (int j = 0; j < NP; ++j) {
    acc2[j].x += __shfl_xor(acc2[j].x, 16, 64);
    acc2[j].x += __shfl_xor(acc2[j].x, 32, 64);
    acc2[j].y += __shfl_xor(acc2[j].y, 16, 64);
    acc2[j].y += __shfl_xor(acc2[j].y, 32, 64);
  }
  if (half == 1) {
    if (lane == 0) { sm[nloc] = m; ss[nloc] = s; }
    if (lane < 16) {
#pragma unroll
      for (int j = 0; j < NP; ++j) {
        sacc[nloc][ch0 + 2 * j] = acc2[j].x;
        sacc[nloc][ch0 + 2 * j + 1] = acc2[j].y;
      }
    }
  }
  __syncthreads();
  if (half == 0 && lane < 16) {
    const float m1 = sm[nloc], s1 = ss[nloc];
    const float mt = fmaxf(m, m1);
    const float f0 = __expf(m - mt);
    const float f1 = __expf(m1 - mt);
    const float st = s * f0 + s1 * f1;
    const float inv = 1.f / (st + 1e-16f);
    float vo[NCH];
#pragma unroll
    for (int k = 0; k < NCH; ++k) {
      const float a = (k & 1) ? acc2[k >> 1].y : acc2[k >> 1].x;
      float v = (a * f0 + sacc[nloc][ch0 + k] * f1) * inv + bias[ch0 + k];
      v = (v > 0.f) ? v : 0.f;
      if (FINAL) v = 1.f / (1.f + __expf(-v));
      vo[k] = v;
    }
    if (FINAL) {
      float* op = (float*)outp + (size_t)node * O + ch0;
#pragma unroll
      for (int k = 0; k < NCH; k += 4)
        *(float4*)(op + k) = make_float4(vo[k], vo[k + 1], vo[k + 2], vo[k + 3]);
    } else {
      unsigned short* op = (unsigned short*)outp + (size_t)node * O + ch0;
#pragma unroll
      for (int v8 = 0; v8 < NCH / 8; ++v8) {
        ushort8 o;
#pragma unroll
        for (int k = 0; k < 8; ++k) o[k] = f2bu(vo[v8 * 8 + k]);
        *(ushort8*)(op + v8 * 8) = o;
      }
    }
  }
}

// ---------------- launch ----------------

extern "C" void kernel_launch(void* const* d_in, const int* in_sizes, int n_in,
                              void* d_out, int out_size, void* d_ws, size_t ws_size,
                              hipStream_t stream) {
  const float* x = (const float*)d_in[0];
  const int* ei = (const int*)d_in[1];
  const int E = in_sizes[1] / 2;
  const int* src = ei;
  const int* dst = ei + E;
  const float* Wl[3] = {(const float*)d_in[2], (const float*)d_in[6], (const float*)d_in[10]};
  const float* Wr[3] = {(const float*)d_in[3], (const float*)d_in[7], (const float*)d_in[11]};
  const float* att[3] = {(const float*)d_in[4], (const float*)d_in[8], (const float*)d_in[12]};
  const float* bia[3] = {(const float*)d_in[5], (const float*)d_in[9], (const float*)d_in[13]};

  char* ws = (char*)d_ws;
  size_t off = 0;
  auto alloc = [&](size_t bytes) -> void* {
    void* p = ws + off;
    off = (off + bytes + 255) & ~(size_t)255;
    return p;
  };
  int* cnt = (int*)alloc((size_t)N_NODES * CSTRIDE * sizeof(int));
  int* csr_pad = (int*)alloc((size_t)N_NODES * CAP * sizeof(int));
  unsigned short* xlb = (unsigned short*)alloc((size_t)N_NODES * 256 * 2);
  unsigned short* xrb = (unsigned short*)alloc((size_t)N_NODES * 256 * 2);
  unsigned short* xb = (unsigned short*)alloc((size_t)N_NODES * 128 * 2);
  unsigned short* curb = (unsigned short*)alloc((size_t)N_NODES * 256 * 2);
  unsigned short* wt[6];
  const int wk[6] = {128, 128, 256, 256, 256, 256};
  const int wo[6] = {256, 256, 256, 256, 128, 128};
  for (int i = 0; i < 6; ++i) wt[i] = (unsigned short*)alloc((size_t)wk[i] * wo[i] * 2);

  hipMemsetAsync(cnt, 0, (size_t)N_NODES * CSTRIDE * sizeof(int), stream);

  // ---- fused prep: bucket fill + W transposes + x convert ----
  PrepArgs pa;
  pa.src = src; pa.dst = dst; pa.E = E;
  pa.cnt = cnt; pa.csr_pad = csr_pad;
  const float* wsrc[6] = {Wl[0], Wr[0], Wl[1], Wr[1], Wl[2], Wr[2]};
  int toff = 0;
  for (int i = 0; i < 6; ++i) {
    pa.wsrc[i] = wsrc[i]; pa.wdst[i] = wt[i]; pa.K[i] = wk[i]; pa.O[i] = wo[i];
    pa.toff[i] = toff;
    toff += (wk[i] >> 5) * (wo[i] >> 5);
  }
  pa.x = x; pa.xb = xb; pa.xn4 = N_NODES * 128 / 4;
  pa.FB = (E + 255) / 256;
  pa.WT = toff;
  pa.XB = (pa.xn4 + 255) / 256;
  prep_k<<<pa.FB + pa.WT + pa.XB, 256, 0, stream>>>(pa);

  // ---- layer 0: 128 -> 256 ----
  mfma_gemm_k<128, 256><<<dim3(157, 4, 2), 256, 0, stream>>>(xb, wt[0], wt[1], xlb, xrb);
  agg8_k<256, false><<<N_NODES / 2, 256, 0, stream>>>(xlb, xrb, att[0], bia[0], cnt, csr_pad, curb);

  // ---- layer 1: 256 -> 256 ----
  mfma_gemm_k<256, 256><<<dim3(157, 4, 2), 256, 0, stream>>>(curb, wt[2], wt[3], xlb, xrb);
  agg8_k<256, false><<<N_NODES / 2, 256, 0, stream>>>(xlb, xrb, att[1], bia[1], cnt, csr_pad, curb);

  // ---- layer 2: 256 -> 128 ----
  mfma_gemm_k<256, 128><<<dim3(157, 2, 2), 256, 0, stream>>>(curb, wt[4], wt[5], xlb, xrb);
  agg8_k<128, true><<<N_NODES / 2, 256, 0, stream>>>(xlb, xrb, att[2], bia[2], cnt, csr_pad, d_out);
}

// Round 13
// 185.644 us; speedup vs baseline: 1.0891x; 1.0891x over previous
//
#include <hip/hip_runtime.h>
#include <hip/hip_bf16.h>
#include <math.h>

#define N_NODES 10000
#define CAP 192        // padded bucket capacity per node (max in-degree ~99 here)
#define CSTRIDE 16     // counter stride in ints: one counter per 64B cache line

typedef __attribute__((ext_vector_type(8))) short short8;
typedef __attribute__((ext_vector_type(8))) unsigned short ushort8;
typedef __attribute__((ext_vector_type(4))) unsigned short ushort4v;
typedef __attribute__((ext_vector_type(4))) float f32x4;

__device__ inline float b2f(unsigned short u) {
  union { unsigned int i; float f; } c;
  c.i = ((unsigned int)u) << 16;
  return c.f;
}
__device__ inline unsigned short f2bu(float v) {
  __hip_bfloat16 h = __float2bfloat16(v);
  return *(unsigned short*)&h;
}

// row_ror DPP add: x += rotate-within-row-of-16(x, CTRL). Pure VALU.
template <int CTRL>
__device__ inline float dpp_radd(float x) {
  union { float f; int i; } u, v;
  u.f = x;
  v.i = __builtin_amdgcn_update_dpp(0, u.i, CTRL, 0xf, 0xf, true);
  return x + v.f;
}

// ---------------- fused prep: bucket-fill + W transposes + x convert -------
struct PrepArgs {
  const int* src;
  const int* dst;
  int E;
  int FB, WT, XB;
  int* cnt;        // [N_NODES*CSTRIDE] zeroed; counter at node*CSTRIDE
  int* csr_pad;    // [N_NODES*CAP]
  const float* wsrc[6];
  unsigned short* wdst[6];
  int K[6], O[6], toff[6];
  const float* x;
  unsigned short* xb;
  int xn4;
};

__global__ void __launch_bounds__(256) prep_k(PrepArgs a) {
  const int bx = blockIdx.x;
  const int tid = threadIdx.x;
  if (bx < a.FB) {  // ---- bucket fill ----
    const int i = bx * 256 + tid;
    if (i < a.E) {
      const int d = a.dst[i];
      const int pos = atomicAdd(&a.cnt[d * CSTRIDE], 1);
      if (pos < CAP) a.csr_pad[d * CAP + pos] = a.src[i];
    }
  } else if (bx < a.FB + a.WT) {  // ---- W transpose, 32x32 tile ----
    const int t = bx - a.FB;
    int m = 0;
#pragma unroll
    for (int i = 1; i < 6; ++i) m += (t >= a.toff[i]);
    const int K = a.K[m], O = a.O[m];
    const int tl = t - a.toff[m];
    const int tilesO = O >> 5;
    const int k0 = (tl / tilesO) << 5;
    const int o0 = (tl - (tl / tilesO) * tilesO) << 5;
    __shared__ float lds[32][33];
    const float* s = a.wsrc[m];
    unsigned short* d = a.wdst[m];
    const int c = tid & 31, r8 = tid >> 5;
#pragma unroll
    for (int p = 0; p < 4; ++p) {
      const int r = p * 8 + r8;
      lds[r][c] = s[(size_t)(k0 + r) * O + o0 + c];  // coalesced f32 read
    }
    __syncthreads();
#pragma unroll
    for (int p = 0; p < 4; ++p) {
      const int rr = p * 8 + r8;
      d[(size_t)(o0 + rr) * K + k0 + c] = f2bu(lds[c][rr]);  // coalesced write
    }
  } else {  // ---- x convert ----
    const int i4 = (bx - a.FB - a.WT) * 256 + tid;
    if (i4 < a.xn4) {
      const float4 v = ((const float4*)a.x)[i4];
      ushort4v o;
      o.x = f2bu(v.x); o.y = f2bu(v.y); o.z = f2bu(v.z); o.w = f2bu(v.w);
      *(ushort4v*)&a.xb[(size_t)i4 * 4] = o;
    }
  }
}

// ---------------- bf16 MFMA GEMM with B-tile staged in LDS ----------------

template <int K, int O>
__global__ void __launch_bounds__(256) mfma_gemm_k(
    const unsigned short* __restrict__ Xb, const unsigned short* __restrict__ WtL,
    const unsigned short* __restrict__ WtR, unsigned short* __restrict__ xlb,
    unsigned short* __restrict__ xrb) {
  constexpr int BSTR = K + 8;  // LDS row stride (ushorts)
  __shared__ unsigned short Bs[64 * BSTR];
  const int tid = threadIdx.x;
  const int wv = tid >> 6, lane = tid & 63;
  const int rowBase = blockIdx.x * 64 + wv * 16;
  const int colBase = blockIdx.y * 64;
  const unsigned short* __restrict__ Wt = blockIdx.z ? WtR : WtL;
  unsigned short* __restrict__ Y = blockIdx.z ? xrb : xlb;
  const int lr = lane & 15, lh = lane >> 4;

  {
    const unsigned short* bsrc = Wt + (size_t)colBase * K;
    constexpr int CHUNKS = 64 * K / 8;
#pragma unroll
    for (int c8 = 0; c8 < CHUNKS / 256; ++c8) {
      const int chunk = c8 * 256 + tid;
      const int r = chunk / (K / 8);
      const int o = (chunk - r * (K / 8)) * 8;
      *(ushort8*)&Bs[r * BSTR + o] = *(const ushort8*)&bsrc[(size_t)r * K + o];
    }
  }
  __syncthreads();

  int arow = rowBase + lr;
  if (arow >= N_NODES) arow = 0;  // clamp (loads only; stores guarded)
  const unsigned short* __restrict__ aptr = Xb + (size_t)arow * K + lh * 8;

  f32x4 acc[4] = {f32x4{0,0,0,0}, f32x4{0,0,0,0}, f32x4{0,0,0,0}, f32x4{0,0,0,0}};
#pragma unroll
  for (int kt = 0; kt < K; kt += 32) {
    const short8 a = *(const short8*)(aptr + kt);
#pragma unroll
    for (int c = 0; c < 4; ++c) {
      const short8 b = *(const short8*)&Bs[(c * 16 + lr) * BSTR + kt + lh * 8];
      acc[c] = __builtin_amdgcn_mfma_f32_16x16x32_bf16(a, b, acc[c], 0, 0, 0);
    }
  }
#pragma unroll
  for (int c = 0; c < 4; ++c) {
#pragma unroll
    for (int q = 0; q < 4; ++q) {
      const int r = rowBase + lh * 4 + q;
      if (r < N_NODES) Y[(size_t)r * O + colBase + c * 16 + lr] = f2bu(acc[c][q]);
    }
  }
}

// ---------------- per-dst-node online-softmax aggregation v9 ----------------
// R7/R11 structure (DPP row-sums, defer-max THR=8, deferred s/acc collapse,
// 2 nodes x 2 half-lists, padded buckets) with ring depth 4:
// rows issued 4 groups ahead, indices 8 ahead.

template <int O, bool FINAL>
__global__ void __launch_bounds__(256, 4) agg9_k(
    const unsigned short* __restrict__ xlb, const unsigned short* __restrict__ xrb,
    const float* __restrict__ att, const float* __restrict__ bias,
    const int* __restrict__ cnt, const int* __restrict__ csr_pad,
    void* __restrict__ outp) {
  constexpr int NCH = O / 16;
  __shared__ float sm[2], ss[2], sacc[2][O];
  const int tid = threadIdx.x;
  const int wv = tid >> 6;
  const int lane = tid & 63;
  const int nloc = wv >> 1;
  const int half = wv & 1;
  const int node = blockIdx.x * 2 + nloc;
  const int cl = lane & 15;   // channel group (low bits -> DPP row = edge)
  const int e_sub = lane >> 4;
  const int ch0 = cl * NCH;

  float av[NCH], xrv[NCH], acc[NCH];
#pragma unroll
  for (int k = 0; k < NCH; ++k) {
    av[k] = att[ch0 + k];
    xrv[k] = b2f(xrb[(size_t)node * O + ch0 + k]);
    acc[k] = 0.f;
  }
  const int beg = node * CAP;
  const int deg = min(cnt[node * CSTRIDE], CAP);
  const int h0 = (deg + 1) >> 1;
  const int b = half ? beg + h0 : beg;
  const int e_end = half ? beg + deg : beg + h0;

  float m = -INFINITY, s = 0.f;
  if (b < e_end) {
    const int e_last = e_end - 1;
    const int G = (e_end - b + 3) >> 2;
    const int G4 = ((G + 3) / 4) * 4;
    auto idx_of = [&](int g) -> int {
      int ei = b + 4 * g + e_sub;
      return csr_pad[ei < e_last ? ei : e_last];
    };
    ushort8 lo0, hi0, lo1, hi1, lo2, hi2, lo3, hi3;
    {
      const int i0 = idx_of(0), i1 = idx_of(1), i2 = idx_of(2), i3 = idx_of(3);
      const ushort8* r0 = (const ushort8*)(xlb + (size_t)i0 * O + ch0);
      const ushort8* r1 = (const ushort8*)(xlb + (size_t)i1 * O + ch0);
      const ushort8* r2 = (const ushort8*)(xlb + (size_t)i2 * O + ch0);
      const ushort8* r3 = (const ushort8*)(xlb + (size_t)i3 * O + ch0);
      lo0 = r0[0]; lo1 = r1[0]; lo2 = r2[0]; lo3 = r3[0];
      if constexpr (NCH == 16) { hi0 = r0[1]; hi1 = r1[1]; hi2 = r2[1]; hi3 = r3[1]; }
    }
    int jA = idx_of(4), jB = idx_of(5), jC = idx_of(6), jD = idx_of(7);

    auto step = [&](ushort8& lo, ushort8& hi, int& jref, int g, int gref) {
      float xf[NCH];
#pragma unroll
      for (int k = 0; k < 8; ++k) xf[k] = b2f(lo[k]);
      if constexpr (NCH == 16) {
#pragma unroll
        for (int k = 0; k < 8; ++k) xf[8 + k] = b2f(hi[k]);
      }
      float p1a = 0.f, p1b = 0.f, p2a = 0.f, p2b = 0.f;
#pragma unroll
      for (int k = 0; k < NCH; k += 2) {
        const float ta = xf[k] + xrv[k];
        const float tb = xf[k + 1] + xrv[k + 1];
        p1a = fmaf(av[k], ta, p1a);
        p2a = fmaf(av[k], fabsf(ta), p2a);
        p1b = fmaf(av[k + 1], tb, p1b);
        p2b = fmaf(av[k + 1], fabsf(tb), p2b);
      }
      float p = fmaf(0.6f, p1a + p1b, 0.4f * (p2a + p2b));
      if (b + 4 * g + e_sub >= e_end) p = -INFINITY;
      p = dpp_radd<0x121>(p);
      p = dpp_radd<0x122>(p);
      p = dpp_radd<0x124>(p);
      p = dpp_radd<0x128>(p);
      if (!__all(p <= m + 8.f)) {
        float q = fmaxf(p, __shfl_xor(p, 16, 64));
        q = fmaxf(q, __shfl_xor(q, 32, 64));
        const float f = __expf(m - q);
        s *= f;
#pragma unroll
        for (int k = 0; k < NCH; ++k) acc[k] *= f;
        m = q;
      }
      const float w = __expf(p - m);
      s += w;
#pragma unroll
      for (int k = 0; k < NCH; ++k) acc[k] = fmaf(w, xf[k], acc[k]);
      // reissue rows for g+4 into this slot, idx for g+8
      const ushort8* rp = (const ushort8*)(xlb + (size_t)jref * O + ch0);
      lo = rp[0];
      if constexpr (NCH == 16) hi = rp[1];
      jref = idx_of(gref);
    };

    for (int g = 0; g < G4; g += 4) {
      step(lo0, hi0, jA, g, g + 8);
      step(lo1, hi1, jB, g + 1, g + 9);
      step(lo2, hi2, jC, g + 2, g + 10);
      step(lo3, hi3, jD, g + 3, g + 11);
    }
  }
  s += __shfl_xor(s, 16, 64);
  s += __shfl_xor(s, 32, 64);
#pragma unroll
  for (int k = 0; k < NCH; ++k) {
    acc[k] += __shfl_xor(acc[k], 16, 64);
    acc[k] += __shfl_xor(acc[k], 32, 64);
  }
  if (half == 1) {
    if (lane == 0) { sm[nloc] = m; ss[nloc] = s; }
    if (lane < 16) {
#pragma unroll
      for (int k = 0; k < NCH; ++k) sacc[nloc][ch0 + k] = acc[k];
    }
  }
  __syncthreads();
  if (half == 0 && lane < 16) {
    const float m1 = sm[nloc], s1 = ss[nloc];
    const float mt = fmaxf(m, m1);
    const float f0 = __expf(m - mt);
    const float f1 = __expf(m1 - mt);
    const float st = s * f0 + s1 * f1;
    const float inv = 1.f / (st + 1e-16f);
    float vo[NCH];
#pragma unroll
    for (int k = 0; k < NCH; ++k) {
      float v = (acc[k] * f0 + sacc[nloc][ch0 + k] * f1) * inv + bias[ch0 + k];
      v = (v > 0.f) ? v : 0.f;
      if (FINAL) v = 1.f / (1.f + __expf(-v));
      vo[k] = v;
    }
    if (FINAL) {
      float* op = (float*)outp + (size_t)node * O + ch0;
#pragma unroll
      for (int k = 0; k < NCH; k += 4)
        *(float4*)(op + k) = make_float4(vo[k], vo[k + 1], vo[k + 2], vo[k + 3]);
    } else {
      unsigned short* op = (unsigned short*)outp + (size_t)node * O + ch0;
#pragma unroll
      for (int v8 = 0; v8 < NCH / 8; ++v8) {
        ushort8 o;
#pragma unroll
        for (int k = 0; k < 8; ++k) o[k] = f2bu(vo[v8 * 8 + k]);
        *(ushort8*)(op + v8 * 8) = o;
      }
    }
  }
}

// ---------------- launch ----------------

extern "C" void kernel_launch(void* const* d_in, const int* in_sizes, int n_in,
                              void* d_out, int out_size, void* d_ws, size_t ws_size,
                              hipStream_t stream) {
  const float* x = (const float*)d_in[0];
  const int* ei = (const int*)d_in[1];
  const int E = in_sizes[1] / 2;
  const int* src = ei;
  const int* dst = ei + E;
  const float* Wl[3] = {(const float*)d_in[2], (const float*)d_in[6], (const float*)d_in[10]};
  const float* Wr[3] = {(const float*)d_in[3], (const float*)d_in[7], (const float*)d_in[11]};
  const float* att[3] = {(const float*)d_in[4], (const float*)d_in[8], (const float*)d_in[12]};
  const float* bia[3] = {(const float*)d_in[5], (const float*)d_in[9], (const float*)d_in[13]};

  char* ws = (char*)d_ws;
  size_t off = 0;
  auto alloc = [&](size_t bytes) -> void* {
    void* p = ws + off;
    off = (off + bytes + 255) & ~(size_t)255;
    return p;
  };
  int* cnt = (int*)alloc((size_t)N_NODES * CSTRIDE * sizeof(int));
  int* csr_pad = (int*)alloc((size_t)N_NODES * CAP * sizeof(int));
  unsigned short* xlb = (unsigned short*)alloc((size_t)N_NODES * 256 * 2);
  unsigned short* xrb = (unsigned short*)alloc((size_t)N_NODES * 256 * 2);
  unsigned short* xb = (unsigned short*)alloc((size_t)N_NODES * 128 * 2);
  unsigned short* curb = (unsigned short*)alloc((size_t)N_NODES * 256 * 2);
  unsigned short* wt[6];
  const int wk[6] = {128, 128, 256, 256, 256, 256};
  const int wo[6] = {256, 256, 256, 256, 128, 128};
  for (int i = 0; i < 6; ++i) wt[i] = (unsigned short*)alloc((size_t)wk[i] * wo[i] * 2);

  hipMemsetAsync(cnt, 0, (size_t)N_NODES * CSTRIDE * sizeof(int), stream);

  // ---- fused prep: bucket fill + W transposes + x convert ----
  PrepArgs pa;
  pa.src = src; pa.dst = dst; pa.E = E;
  pa.cnt = cnt; pa.csr_pad = csr_pad;
  const float* wsrc[6] = {Wl[0], Wr[0], Wl[1], Wr[1], Wl[2], Wr[2]};
  int toff = 0;
  for (int i = 0; i < 6; ++i) {
    pa.wsrc[i] = wsrc[i]; pa.wdst[i] = wt[i]; pa.K[i] = wk[i]; pa.O[i] = wo[i];
    pa.toff[i] = toff;
    toff += (wk[i] >> 5) * (wo[i] >> 5);
  }
  pa.x = x; pa.xb = xb; pa.xn4 = N_NODES * 128 / 4;
  pa.FB = (E + 255) / 256;
  pa.WT = toff;
  pa.XB = (pa.xn4 + 255) / 256;
  prep_k<<<pa.FB + pa.WT + pa.XB, 256, 0, stream>>>(pa);

  // ---- layer 0: 128 -> 256 ----
  mfma_gemm_k<128, 256><<<dim3(157, 4, 2), 256, 0, stream>>>(xb, wt[0], wt[1], xlb, xrb);
  agg9_k<256, false><<<N_NODES / 2, 256, 0, stream>>>(xlb, xrb, att[0], bia[0], cnt, csr_pad, curb);

  // ---- layer 1: 256 -> 256 ----
  mfma_gemm_k<256, 256><<<dim3(157, 4, 2), 256, 0, stream>>>(curb, wt[2], wt[3], xlb, xrb);
  agg9_k<256, false><<<N_NODES / 2, 256, 0, stream>>>(xlb, xrb, att[1], bia[1], cnt, csr_pad, curb);

  // ---- layer 2: 256 -> 128 ----
  mfma_gemm_k<256, 128><<<dim3(157, 2, 2), 256, 0, stream>>>(curb, wt[4], wt[5], xlb, xrb);
  agg9_k<128, true><<<N_NODES / 2, 256, 0, stream>>>(xlb, xrb, att[2], bia[2], cnt, csr_pad, d_out);
}

// Round 14
// 174.995 us; speedup vs baseline: 1.1554x; 1.0609x over previous
//
#include <hip/hip_runtime.h>
#include <hip/hip_bf16.h>
#include <math.h>

#define N_NODES 10000
#define CAP 192        // padded bucket capacity per node (max in-degree ~99 here)
#define CSTRIDE 16     // counter stride in ints: one counter per 64B cache line

typedef __attribute__((ext_vector_type(8))) short short8;
typedef __attribute__((ext_vector_type(8))) unsigned short ushort8;
typedef __attribute__((ext_vector_type(4))) unsigned short ushort4v;
typedef __attribute__((ext_vector_type(4))) float f32x4;

__device__ inline float b2f(unsigned short u) {
  union { unsigned int i; float f; } c;
  c.i = ((unsigned int)u) << 16;
  return c.f;
}
__device__ inline unsigned short f2bu(float v) {
  __hip_bfloat16 h = __float2bfloat16(v);
  return *(unsigned short*)&h;
}

// row_ror DPP add: x += rotate-within-row-of-16(x, CTRL). Pure VALU.
template <int CTRL>
__device__ inline float dpp_radd(float x) {
  union { float f; int i; } u, v;
  u.f = x;
  v.i = __builtin_amdgcn_update_dpp(0, u.i, CTRL, 0xf, 0xf, true);
  return x + v.f;
}

// ---------------- fused prep: bucket-fill + W transposes + x convert -------
struct PrepArgs {
  const int* src;
  const int* dst;
  int E;
  int FB, WT, XB;
  int* cnt;        // [N_NODES*CSTRIDE] zeroed; counter at node*CSTRIDE
  int* csr_pad;    // [N_NODES*CAP]
  const float* wsrc[6];
  unsigned short* wdst[6];
  int K[6], O[6], toff[6];
  const float* x;
  unsigned short* xb;
  int xn4;
};

__global__ void __launch_bounds__(256) prep_k(PrepArgs a) {
  const int bx = blockIdx.x;
  const int tid = threadIdx.x;
  if (bx < a.FB) {  // ---- bucket fill ----
    const int i = bx * 256 + tid;
    if (i < a.E) {
      const int d = a.dst[i];
      const int pos = atomicAdd(&a.cnt[d * CSTRIDE], 1);
      if (pos < CAP) a.csr_pad[d * CAP + pos] = a.src[i];
    }
  } else if (bx < a.FB + a.WT) {  // ---- W transpose, 32x32 tile ----
    const int t = bx - a.FB;
    int m = 0;
#pragma unroll
    for (int i = 1; i < 6; ++i) m += (t >= a.toff[i]);
    const int K = a.K[m], O = a.O[m];
    const int tl = t - a.toff[m];
    const int tilesO = O >> 5;
    const int k0 = (tl / tilesO) << 5;
    const int o0 = (tl - (tl / tilesO) * tilesO) << 5;
    __shared__ float lds[32][33];
    const float* s = a.wsrc[m];
    unsigned short* d = a.wdst[m];
    const int c = tid & 31, r8 = tid >> 5;
#pragma unroll
    for (int p = 0; p < 4; ++p) {
      const int r = p * 8 + r8;
      lds[r][c] = s[(size_t)(k0 + r) * O + o0 + c];  // coalesced f32 read
    }
    __syncthreads();
#pragma unroll
    for (int p = 0; p < 4; ++p) {
      const int rr = p * 8 + r8;
      d[(size_t)(o0 + rr) * K + k0 + c] = f2bu(lds[c][rr]);  // coalesced write
    }
  } else {  // ---- x convert ----
    const int i4 = (bx - a.FB - a.WT) * 256 + tid;
    if (i4 < a.xn4) {
      const float4 v = ((const float4*)a.x)[i4];
      ushort4v o;
      o.x = f2bu(v.x); o.y = f2bu(v.y); o.z = f2bu(v.z); o.w = f2bu(v.w);
      *(ushort4v*)&a.xb[(size_t)i4 * 4] = o;
    }
  }
}

// ---------------- bf16 MFMA GEMM with B-tile staged in LDS ----------------

template <int K, int O>
__global__ void __launch_bounds__(256) mfma_gemm_k(
    const unsigned short* __restrict__ Xb, const unsigned short* __restrict__ WtL,
    const unsigned short* __restrict__ WtR, unsigned short* __restrict__ xlb,
    unsigned short* __restrict__ xrb) {
  constexpr int BSTR = K + 8;  // LDS row stride (ushorts)
  __shared__ unsigned short Bs[64 * BSTR];
  const int tid = threadIdx.x;
  const int wv = tid >> 6, lane = tid & 63;
  const int rowBase = blockIdx.x * 64 + wv * 16;
  const int colBase = blockIdx.y * 64;
  const unsigned short* __restrict__ Wt = blockIdx.z ? WtR : WtL;
  unsigned short* __restrict__ Y = blockIdx.z ? xrb : xlb;
  const int lr = lane & 15, lh = lane >> 4;

  {
    const unsigned short* bsrc = Wt + (size_t)colBase * K;
    constexpr int CHUNKS = 64 * K / 8;
#pragma unroll
    for (int c8 = 0; c8 < CHUNKS / 256; ++c8) {
      const int chunk = c8 * 256 + tid;
      const int r = chunk / (K / 8);
      const int o = (chunk - r * (K / 8)) * 8;
      *(ushort8*)&Bs[r * BSTR + o] = *(const ushort8*)&bsrc[(size_t)r * K + o];
    }
  }
  __syncthreads();

  int arow = rowBase + lr;
  if (arow >= N_NODES) arow = 0;  // clamp (loads only; stores guarded)
  const unsigned short* __restrict__ aptr = Xb + (size_t)arow * K + lh * 8;

  f32x4 acc[4] = {f32x4{0,0,0,0}, f32x4{0,0,0,0}, f32x4{0,0,0,0}, f32x4{0,0,0,0}};
#pragma unroll
  for (int kt = 0; kt < K; kt += 32) {
    const short8 a = *(const short8*)(aptr + kt);
#pragma unroll
    for (int c = 0; c < 4; ++c) {
      const short8 b = *(const short8*)&Bs[(c * 16 + lr) * BSTR + kt + lh * 8];
      acc[c] = __builtin_amdgcn_mfma_f32_16x16x32_bf16(a, b, acc[c], 0, 0, 0);
    }
  }
#pragma unroll
  for (int c = 0; c < 4; ++c) {
#pragma unroll
    for (int q = 0; q < 4; ++q) {
      const int r = rowBase + lh * 4 + q;
      if (r < N_NODES) Y[(size_t)r * O + colBase + c * 16 + lr] = f2bu(acc[c][q]);
    }
  }
}

// ---------------- per-dst-node online-softmax aggregation v7b ----------------
// R7/R11 structure: DPP row-sums, defer-max THR=8, deferred s/acc collapse,
// depth-3 ring (rows +3 groups ahead, idx +6), 2 nodes x 2 half-lists,
// padded buckets. Best-measured configuration (R11: 46.8 us @ O=256).

template <int O, bool FINAL>
__global__ void __launch_bounds__(256, 4) agg7_k(
    const unsigned short* __restrict__ xlb, const unsigned short* __restrict__ xrb,
    const float* __restrict__ att, const float* __restrict__ bias,
    const int* __restrict__ cnt, const int* __restrict__ csr_pad,
    void* __restrict__ outp) {
  constexpr int NCH = O / 16;
  __shared__ float sm[2], ss[2], sacc[2][O];
  const int tid = threadIdx.x;
  const int wv = tid >> 6;
  const int lane = tid & 63;
  const int nloc = wv >> 1;
  const int half = wv & 1;
  const int node = blockIdx.x * 2 + nloc;
  const int cl = lane & 15;
  const int e_sub = lane >> 4;
  const int ch0 = cl * NCH;

  float av[NCH], xrv[NCH], acc[NCH];
#pragma unroll
  for (int k = 0; k < NCH; ++k) {
    av[k] = att[ch0 + k];
    xrv[k] = b2f(xrb[(size_t)node * O + ch0 + k]);
    acc[k] = 0.f;
  }
  const int beg = node * CAP;
  const int deg = min(cnt[node * CSTRIDE], CAP);
  const int h0 = (deg + 1) >> 1;
  const int b = half ? beg + h0 : beg;
  const int e_end = half ? beg + deg : beg + h0;

  float m = -INFINITY, s = 0.f;
  if (b < e_end) {
    const int e_last = e_end - 1;
    const int G = (e_end - b + 3) >> 2;
    const int G3 = ((G + 2) / 3) * 3;
    auto idx_of = [&](int g) -> int {
      int ei = b + 4 * g + e_sub;
      return csr_pad[ei < e_last ? ei : e_last];
    };
    ushort8 lo0, hi0, lo1, hi1, lo2, hi2;
    {
      const int i0 = idx_of(0), i1 = idx_of(1), i2 = idx_of(2);
      const ushort8* r0 = (const ushort8*)(xlb + (size_t)i0 * O + ch0);
      const ushort8* r1 = (const ushort8*)(xlb + (size_t)i1 * O + ch0);
      const ushort8* r2 = (const ushort8*)(xlb + (size_t)i2 * O + ch0);
      lo0 = r0[0]; lo1 = r1[0]; lo2 = r2[0];
      if constexpr (NCH == 16) { hi0 = r0[1]; hi1 = r1[1]; hi2 = r2[1]; }
    }
    int jA = idx_of(3), jB = idx_of(4), jC = idx_of(5);

    auto step = [&](ushort8& lo, ushort8& hi, int& jref, int g, int gref) {
      float xf[NCH];
#pragma unroll
      for (int k = 0; k < 8; ++k) xf[k] = b2f(lo[k]);
      if constexpr (NCH == 16) {
#pragma unroll
        for (int k = 0; k < 8; ++k) xf[8 + k] = b2f(hi[k]);
      }
      float p1a = 0.f, p1b = 0.f, p2a = 0.f, p2b = 0.f;
#pragma unroll
      for (int k = 0; k < NCH; k += 2) {
        const float ta = xf[k] + xrv[k];
        const float tb = xf[k + 1] + xrv[k + 1];
        p1a = fmaf(av[k], ta, p1a);
        p2a = fmaf(av[k], fabsf(ta), p2a);
        p1b = fmaf(av[k + 1], tb, p1b);
        p2b = fmaf(av[k + 1], fabsf(tb), p2b);
      }
      float p = fmaf(0.6f, p1a + p1b, 0.4f * (p2a + p2b));
      if (b + 4 * g + e_sub >= e_end) p = -INFINITY;
      p = dpp_radd<0x121>(p);
      p = dpp_radd<0x122>(p);
      p = dpp_radd<0x124>(p);
      p = dpp_radd<0x128>(p);
      if (!__all(p <= m + 8.f)) {
        float q = fmaxf(p, __shfl_xor(p, 16, 64));
        q = fmaxf(q, __shfl_xor(q, 32, 64));
        const float f = __expf(m - q);
        s *= f;
#pragma unroll
        for (int k = 0; k < NCH; ++k) acc[k] *= f;
        m = q;
      }
      const float w = __expf(p - m);
      s += w;
#pragma unroll
      for (int k = 0; k < NCH; ++k) acc[k] = fmaf(w, xf[k], acc[k]);
      const ushort8* rp = (const ushort8*)(xlb + (size_t)jref * O + ch0);
      lo = rp[0];
      if constexpr (NCH == 16) hi = rp[1];
      jref = idx_of(gref);
    };

    for (int g = 0; g < G3; g += 3) {
      step(lo0, hi0, jA, g, g + 6);
      step(lo1, hi1, jB, g + 1, g + 7);
      step(lo2, hi2, jC, g + 2, g + 8);
    }
  }
  s += __shfl_xor(s, 16, 64);
  s += __shfl_xor(s, 32, 64);
#pragma unroll
  for (int k = 0; k < NCH; ++k) {
    acc[k] += __shfl_xor(acc[k], 16, 64);
    acc[k] += __shfl_xor(acc[k], 32, 64);
  }
  if (half == 1) {
    if (lane == 0) { sm[nloc] = m; ss[nloc] = s; }
    if (lane < 16) {
#pragma unroll
      for (int k = 0; k < NCH; ++k) sacc[nloc][ch0 + k] = acc[k];
    }
  }
  __syncthreads();
  if (half == 0 && lane < 16) {
    const float m1 = sm[nloc], s1 = ss[nloc];
    const float mt = fmaxf(m, m1);
    const float f0 = __expf(m - mt);
    const float f1 = __expf(m1 - mt);
    const float st = s * f0 + s1 * f1;
    const float inv = 1.f / (st + 1e-16f);
    float vo[NCH];
#pragma unroll
    for (int k = 0; k < NCH; ++k) {
      float v = (acc[k] * f0 + sacc[nloc][ch0 + k] * f1) * inv + bias[ch0 + k];
      v = (v > 0.f) ? v : 0.f;
      if (FINAL) v = 1.f / (1.f + __expf(-v));
      vo[k] = v;
    }
    if (FINAL) {
      float* op = (float*)outp + (size_t)node * O + ch0;
#pragma unroll
      for (int k = 0; k < NCH; k += 4)
        *(float4*)(op + k) = make_float4(vo[k], vo[k + 1], vo[k + 2], vo[k + 3]);
    } else {
      unsigned short* op = (unsigned short*)outp + (size_t)node * O + ch0;
#pragma unroll
      for (int v8 = 0; v8 < NCH / 8; ++v8) {
        ushort8 o;
#pragma unroll
        for (int k = 0; k < 8; ++k) o[k] = f2bu(vo[v8 * 8 + k]);
        *(ushort8*)(op + v8 * 8) = o;
      }
    }
  }
}

// ---------------- launch ----------------

extern "C" void kernel_launch(void* const* d_in, const int* in_sizes, int n_in,
                              void* d_out, int out_size, void* d_ws, size_t ws_size,
                              hipStream_t stream) {
  const float* x = (const float*)d_in[0];
  const int* ei = (const int*)d_in[1];
  const int E = in_sizes[1] / 2;
  const int* src = ei;
  const int* dst = ei + E;
  const float* Wl[3] = {(const float*)d_in[2], (const float*)d_in[6], (const float*)d_in[10]};
  const float* Wr[3] = {(const float*)d_in[3], (const float*)d_in[7], (const float*)d_in[11]};
  const float* att[3] = {(const float*)d_in[4], (const float*)d_in[8], (const float*)d_in[12]};
  const float* bia[3] = {(const float*)d_in[5], (const float*)d_in[9], (const float*)d_in[13]};

  char* ws = (char*)d_ws;
  size_t off = 0;
  auto alloc = [&](size_t bytes) -> void* {
    void* p = ws + off;
    off = (off + bytes + 255) & ~(size_t)255;
    return p;
  };
  int* cnt = (int*)alloc((size_t)N_NODES * CSTRIDE * sizeof(int));
  int* csr_pad = (int*)alloc((size_t)N_NODES * CAP * sizeof(int));
  unsigned short* xlb = (unsigned short*)alloc((size_t)N_NODES * 256 * 2);
  unsigned short* xrb = (unsigned short*)alloc((size_t)N_NODES * 256 * 2);
  unsigned short* xb = (unsigned short*)alloc((size_t)N_NODES * 128 * 2);
  unsigned short* curb = (unsigned short*)alloc((size_t)N_NODES * 256 * 2);
  unsigned short* wt[6];
  const int wk[6] = {128, 128, 256, 256, 256, 256};
  const int wo[6] = {256, 256, 256, 256, 128, 128};
  for (int i = 0; i < 6; ++i) wt[i] = (unsigned short*)alloc((size_t)wk[i] * wo[i] * 2);

  hipMemsetAsync(cnt, 0, (size_t)N_NODES * CSTRIDE * sizeof(int), stream);

  // ---- fused prep: bucket fill + W transposes + x convert ----
  PrepArgs pa;
  pa.src = src; pa.dst = dst; pa.E = E;
  pa.cnt = cnt; pa.csr_pad = csr_pad;
  const float* wsrc[6] = {Wl[0], Wr[0], Wl[1], Wr[1], Wl[2], Wr[2]};
  int toff = 0;
  for (int i = 0; i < 6; ++i) {
    pa.wsrc[i] = wsrc[i]; pa.wdst[i] = wt[i]; pa.K[i] = wk[i]; pa.O[i] = wo[i];
    pa.toff[i] = toff;
    toff += (wk[i] >> 5) * (wo[i] >> 5);
  }
  pa.x = x; pa.xb = xb; pa.xn4 = N_NODES * 128 / 4;
  pa.FB = (E + 255) / 256;
  pa.WT = toff;
  pa.XB = (pa.xn4 + 255) / 256;
  prep_k<<<pa.FB + pa.WT + pa.XB, 256, 0, stream>>>(pa);

  // ---- layer 0: 128 -> 256 ----
  mfma_gemm_k<128, 256><<<dim3(157, 4, 2), 256, 0, stream>>>(xb, wt[0], wt[1], xlb, xrb);
  agg7_k<256, false><<<N_NODES / 2, 256, 0, stream>>>(xlb, xrb, att[0], bia[0], cnt, csr_pad, curb);

  // ---- layer 1: 256 -> 256 ----
  mfma_gemm_k<256, 256><<<dim3(157, 4, 2), 256, 0, stream>>>(curb, wt[2], wt[3], xlb, xrb);
  agg7_k<256, false><<<N_NODES / 2, 256, 0, stream>>>(xlb, xrb, att[1], bia[1], cnt, csr_pad, curb);

  // ---- layer 2: 256 -> 128 ----
  mfma_gemm_k<256, 128><<<dim3(157, 2, 2), 256, 0, stream>>>(curb, wt[4], wt[5], xlb, xrb);
  agg7_k<128, true><<<N_NODES / 2, 256, 0, stream>>>(xlb, xrb, att[2], bia[2], cnt, csr_pad, d_out);
}